// Round 4
// baseline (412.447 us; speedup 1.0000x reference)
//
#include <hip/hip_runtime.h>

// IPLS partial_fit (n > BURN_IN). Gram-reformulated:
//   x-side Gram 65x65 of [xc, P_0..31, Wz_0..31], y-side 33x33 of [yc, Cz_0..31]
//   -> 1-wave f64 scalar recurrence solve -> skinny 64x33 output combine.
// R4: gram uses 128-float LDS windows (34.8KB -> 2 blocks/CU); out_kernel is
// j-outer with 64 resident accumulators (no compiler reload of B); solve
// preloads all Gram rows into registers (memory off the critical path).

#define NF 262144
#define NT 8192
#define NL 32
#define GXS 68
#define GYS 36
#define NBX 512          // x-side gram blocks (each: 4 windows of 128 floats)
#define NBY 32           // y-side gram blocks (2 windows of 128)
#define NPAIR 66         // 11 groups of 6 rows -> 66 group-pairs
#define ENT (NPAIR*36)   // 2376 partial entries per block
#define NCH 32           // stage-1 reduce chunks
#define CHSZ (NBX/NCH)   // 16 slices per chunk

#define WS_PART  0
#define WS_PART2 (NBX*ENT)                   // 1216512
#define WS_GY    (WS_PART2 + NCH*ENT)        // 1292544
#define WS_GX    (WS_GY + GYS*GYS)           // 1293840
#define WS_COEF  (WS_GX + GXS*GXS)           // 1298464 (3*32*33 floats, transposed)

#define OUT_MU_X 0
#define OUT_MU_Y 262144
#define OUT_U    270336
#define OUT_WZ   270368
#define OUT_CZ   8658976
#define OUT_TSS  8921120
#define OUT_BZ   8921152
#define OUT_P    8921184

#define LDSW 132   // row stride (floats): 128 + 4 pad

__device__ __forceinline__ float4 ld4(const float* p) { return *(const float4*)p; }

__global__ __launch_bounds__(320) void gram_kernel(
    const float* __restrict__ x, const float* __restrict__ y,
    const float* __restrict__ mux, const float* __restrict__ muy,
    const float* __restrict__ Wz, const float* __restrict__ Cz,
    const float* __restrict__ P, const int* __restrict__ np,
    float* __restrict__ ws)
{
  __shared__ float lds[66 * LDSW];   // 34.8 KB -> 2+ blocks/CU
  const int tid = threadIdx.x;
  const int b = blockIdx.x;
  const float n1 = (float)(np[0] + 1);
  const float cmu = n1 / (n1 + 1.0f);   // xc = cmu*(x - mu_old)

  if (b < NBX) {
    // ---- x-side: 66 rows (xc, P_0..31, Wz_0..31, zero), 6-row groups ----
    const int q = tid & 3;
    const int pidx = tid >> 2;
    int gu = 0, gv = 0; bool active = (tid < 264);
    if (active) {
      int pp = pidx;
      for (int g = 0; g < 11; ++g) {
        int c = 11 - g;
        if (pp < c) { gu = g; gv = g + pp; break; }
        pp -= c;
      }
    }
    float acc[36];
#pragma unroll
    for (int i = 0; i < 36; ++i) acc[i] = 0.f;

    for (int w = 0; w < 4; ++w) {
      const int wb = b * 512 + w * 128;
      // stage 66 rows x 32 float4 (two rows per wave: 512B contiguous halves)
      for (int it = 0; it < 7; ++it) {
        int idx = tid + it * 320;
        if (idx < 2112) {
          int row = idx >> 5;
          int c4 = idx & 31;
          int k = wb + c4 * 4;
          float4 v;
          if (row == 0) {
            float4 xv = ld4(x + k), mv = ld4(mux + k);
            v.x = cmu * (xv.x - mv.x); v.y = cmu * (xv.y - mv.y);
            v.z = cmu * (xv.z - mv.z); v.w = cmu * (xv.w - mv.w);
          } else if (row < 33) {
            v = ld4(P + (size_t)(row - 1) * NF + k);
          } else if (row < 65) {
            v = ld4(Wz + (size_t)(row - 33) * NF + k);
          } else {
            v = make_float4(0.f, 0.f, 0.f, 0.f);
          }
          *(float4*)&lds[row * LDSW + c4 * 4] = v;
        }
      }
      __syncthreads();
      if (active) {
        const int ub = 6 * gu * LDSW, vb = 6 * gv * LDSW;
#pragma unroll
        for (int cc = 0; cc < 8; ++cc) {
          const int co = (q + cc * 4) * 4;
          float4 av[6], bv[6];
#pragma unroll
          for (int r = 0; r < 6; ++r) av[r] = *(const float4*)&lds[ub + r * LDSW + co];
#pragma unroll
          for (int s = 0; s < 6; ++s) bv[s] = *(const float4*)&lds[vb + s * LDSW + co];
#pragma unroll
          for (int r = 0; r < 6; ++r)
#pragma unroll
            for (int s = 0; s < 6; ++s)
              acc[r * 6 + s] += av[r].x * bv[s].x + av[r].y * bv[s].y +
                                av[r].z * bv[s].z + av[r].w * bv[s].w;
        }
      }
      __syncthreads();
    }
    // combine the 4 quarters (adjacent lanes within a wave)
#pragma unroll
    for (int e = 0; e < 36; ++e) {
      acc[e] += __shfl_xor(acc[e], 1, 64);
      acc[e] += __shfl_xor(acc[e], 2, 64);
    }
    if (active && q == 0) {
      float* PB = ws + WS_PART + (size_t)b * ENT + pidx * 36;
#pragma unroll
      for (int e4 = 0; e4 < 9; ++e4)
        *(float4*)&PB[e4 * 4] = make_float4(acc[e4 * 4], acc[e4 * 4 + 1],
                                            acc[e4 * 4 + 2], acc[e4 * 4 + 3]);
    }
  } else {
    // ---- y-side: 36 rows (yc, Cz_0..31, zeros), 4-row groups, 45 pairs ----
    float* GY = ws + WS_GY;
    const int yb = b - NBX;
    int gu = 0, gv = 0; bool active = (tid < 45);
    if (active) {
      int pp = tid;
      for (int g = 0; g < 9; ++g) {
        int c = 9 - g;
        if (pp < c) { gu = g; gv = g + pp; break; }
        pp -= c;
      }
    }
    float acc[16];
#pragma unroll
    for (int i = 0; i < 16; ++i) acc[i] = 0.f;
    for (int w = 0; w < 2; ++w) {
      const int wb = yb * 256 + w * 128;
      for (int it = 0; it < 4; ++it) {
        int idx = tid + it * 320;
        if (idx < 1152) {
          int row = idx >> 5;
          int c4 = idx & 31;
          int k = wb + c4 * 4;
          float4 v;
          if (row == 0) {
            float4 yv = ld4(y + k), mv = ld4(muy + k);
            v.x = cmu * (yv.x - mv.x); v.y = cmu * (yv.y - mv.y);
            v.z = cmu * (yv.z - mv.z); v.w = cmu * (yv.w - mv.w);
          } else if (row < 33) {
            v = ld4(Cz + (size_t)(row - 1) * NT + k);
          } else {
            v = make_float4(0.f, 0.f, 0.f, 0.f);
          }
          *(float4*)&lds[row * LDSW + c4 * 4] = v;
        }
      }
      __syncthreads();
      if (active) {
        const int ub = 4 * gu * LDSW, vb = 4 * gv * LDSW;
        for (int c = 0; c < 32; ++c) {
          float4 av[4], bv[4];
#pragma unroll
          for (int r = 0; r < 4; ++r) av[r] = *(const float4*)&lds[ub + r * LDSW + c * 4];
#pragma unroll
          for (int s = 0; s < 4; ++s) bv[s] = *(const float4*)&lds[vb + s * LDSW + c * 4];
#pragma unroll
          for (int r = 0; r < 4; ++r)
#pragma unroll
            for (int s = 0; s < 4; ++s)
              acc[r * 4 + s] += av[r].x * bv[s].x + av[r].y * bv[s].y +
                                av[r].z * bv[s].z + av[r].w * bv[s].w;
        }
      }
      __syncthreads();
    }
    if (active) {
#pragma unroll
      for (int r = 0; r < 4; ++r)
#pragma unroll
        for (int s = 0; s < 4; ++s) {
          int u = 4 * gu + r, v = 4 * gv + s;
          if (u < 33 && v < 33) {
            float val = acc[r * 4 + s];
            atomicAdd(&GY[u * GYS + v], val);
            if (gu != gv) atomicAdd(&GY[v * GYS + u], val);
          }
        }
    }
  }
}

// stage 1: 512 slices -> 32 chunk partials (coalesced)
__global__ __launch_bounds__(256) void reduce1_kernel(float* __restrict__ ws) {
  const int c = blockIdx.x / 10, eb = blockIdx.x % 10;
  const int e = eb * 256 + threadIdx.x;
  if (e < ENT) {
    const float* PB = ws + WS_PART + (size_t)c * CHSZ * ENT;
    float s = 0.f;
#pragma unroll
    for (int j = 0; j < CHSZ; ++j) s += PB[(size_t)j * ENT + e];
    ws[WS_PART2 + (size_t)c * ENT + e] = s;
  }
}

// stage 2: 32 chunk partials -> GX (scatter to 68x68 mirrored layout)
__global__ __launch_bounds__(256) void reduce2_kernel(float* __restrict__ ws) {
  const int e = blockIdx.x * 256 + threadIdx.x;
  if (e < ENT) {
    float s = 0.f;
#pragma unroll
    for (int c = 0; c < NCH; ++c) s += ws[WS_PART2 + (size_t)c * ENT + e];
    int p = e / 36, rs = e % 36;
    int gu = 0, gv = 0, pp = p;
    for (int g = 0; g < 11; ++g) {
      int cN = 11 - g;
      if (pp < cN) { gu = g; gv = g + pp; break; }
      pp -= cN;
    }
    int u = 6 * gu + rs / 6, v = 6 * gv + rs % 6;
    float* GX = ws + WS_GX;
    GX[u * GXS + v] = s;
    if (gu != gv) GX[v * GXS + u] = s;
  }
}

// One wave: f64 scalar recurrences for all 32 components.
// All Gram rows preloaded into registers; i-loop fully unrolled so register
// arrays stay in VGPRs and __shfl indices are compile-time.
// Coef matrices stored TRANSPOSED: A*T[j*32 + i], j=0..32 basis, i component.
__global__ void solve_kernel(const float* __restrict__ ws,
                             const float* __restrict__ u_in,
                             const float* __restrict__ tss_in,
                             const float* __restrict__ bz_in,
                             float* __restrict__ coef,
                             float* __restrict__ out)
{
  const int l = threadIdx.x;  // 0..63
  const float* GX = ws + WS_GX;
  const float* GY = ws + WS_GY;
  float* AWZT = coef;               // 33 x 32
  float* APT  = coef + 33 * NL;     // 33 x 32 (+P_i identity folded)
  float* ACZT = coef + 66 * NL;     // 33 x 32 (+Cz_i identity folded)

  // ---- preload phase: all loads independent, issued together ----
  float rP[32], rW[32], rC[32];
#pragma unroll
  for (int i = 0; i < 32; ++i) rP[i] = GX[(1 + i) * GXS + 1 + l];
#pragma unroll
  for (int i = 0; i < 32; ++i) rW[i] = GX[(1 + i) * GXS + 33 + l];
#pragma unroll
  for (int i = 0; i < 32; ++i) rC[i] = GY[(1 + i) * GYS + 1 + l];
  float dS  = (l < 32) ? GX[(33 + l) * GXS + 33 + l] : 0.f;  // ||Wz_l||^2
  float u0l = (l < 32) ? u_in[l]   : 0.f;
  float t0l = (l < 32) ? tss_in[l] : 0.f;
  float b0l = (l < 32) ? bz_in[l]  : 0.f;

  double q = (double)GX[0];                       // ||xr||^2
  double r = (double)GY[0];                       // ||yr||^2
  double pj = (l < 32) ? (double)GX[1 + l]  : 0.0;
  double wj = (l < 32) ? (double)GX[33 + l] : 0.0;
  double ej = (l < 32) ? (double)GY[1 + l]  : 0.0;
  double cx = (l == 0) ? 1.0 : 0.0;
  double cy = (l == 0) ? 1.0 : 0.0;

#pragma unroll
  for (int i = 0; i < NL; ++i) {
    double a  = __shfl(wj, i, 64);
    double g  = __shfl(ej, i, 64);
    double pi = __shfl(pj, i, 64);
    double s  = (double)__shfl(dS, i, 64);
    double h  = (double)__shfl(rC[i], i, 64);      // GY diag (1+i,1+i)
    double Pd = (double)__shfl(rP[i], i, 64);      // GX diag (1+i,1+i)
    double u0   = (double)__shfl(u0l, i, 64);
    double tss0 = (double)__shfl(t0l, i, 64);
    double bz0  = (double)__shfl(b0l, i, 64);

    double ui = u0, u1 = 0.0, tz = 0.0, tss_ = 0.0, t = 0.0, ncz = 1.0;
#pragma unroll
    for (int pass = 0; pass < 2; ++pass) {
      double num = a + ui * q;
      double den = sqrt(s + 2.0 * ui * a + ui * ui * q) + 1e-7;
      tz = num / den;
      tss_ = tss0 + tz * tz;
      t = tz / sqrt(tss_);
      double ncz2 = h + 2.0 * t * g + t * t * r;
      ncz = sqrt(ncz2);
      ui = (g + t * r) / ncz;
      if (pass == 0) u1 = ui;
    }
    double u2 = ui;
    double bz_new = bz0 + u2 * tz;
    double bb = bz_new / sqrt(tss_);
    double phi = 1.0 - t * t;            // xr' = phi*xr - t*P_i
    double gam = bb * t / ncz;           // yr' = psi*yr - gam*Cz_i
    double psi = 1.0 - gam * t;

    if (l == 0) {
      out[OUT_U + i]   = (float)u2;
      out[OUT_TSS + i] = (float)tss_;
      out[OUT_BZ + i]  = (float)bz_new;
    }
    if (l < 33) {
      AWZT[l * 32 + i] = (float)(u1 * cx);
      APT [l * 32 + i] = (float)(t  * cx) + ((l == 1 + i) ? 1.0f : 0.0f);
      ACZT[l * 32 + i] = (float)(t  * cy) + ((l == 1 + i) ? 1.0f : 0.0f);
    }
    q = phi * phi * q - 2.0 * phi * t * pi + t * t * Pd;
    r = psi * psi * r - 2.0 * psi * gam * g + gam * gam * h;
    cx *= phi; if (l == 1 + i) cx -= t;
    cy *= psi; if (l == 1 + i) cy -= gam;
    if (l < 32) {
      pj = phi * pj - t * (double)rP[i];
      wj = phi * wj - t * (double)rW[i];
      ej = psi * ej - gam * (double)rC[i];
    }
  }
}

// j-outer, 64 resident f32 accumulators per thread: B_j loaded once, consumed,
// never re-loadable by the compiler (accumulators must stay live).
__global__ __launch_bounds__(256) void out_kernel(
    const float* __restrict__ x, const float* __restrict__ y,
    const float* __restrict__ mux, const float* __restrict__ muy,
    const float* __restrict__ Wz, const float* __restrict__ Cz,
    const float* __restrict__ P, const int* __restrict__ np,
    const float* __restrict__ coef, float* __restrict__ out)
{
  const int b = blockIdx.x, tid = threadIdx.x;
  const float n1 = (float)(np[0] + 1);
  const float inv = 1.0f / (n1 + 1.0f);
  const float* AWZT = coef;
  const float* APT  = coef + 33 * NL;
  const float* ACZT = coef + 66 * NL;

  if (b < 1024) {
    const int k = b * 256 + tid;
    float xv = x[k], mv = mux[k];
    float mn = (mv * n1 + xv) * inv;
    out[OUT_MU_X + k] = mn;
    float accW[32], accP[32];
#pragma unroll
    for (int i = 0; i < 32; ++i) accW[i] = Wz[(size_t)i * NF + k];
#pragma unroll
    for (int i = 0; i < 32; ++i) accP[i] = 0.f;
    {
      float B0 = xv - mn;
#pragma unroll
      for (int i = 0; i < 32; ++i) {
        accW[i] += AWZT[i] * B0;
        accP[i] += APT[i] * B0;
      }
    }
#pragma unroll 4
    for (int j = 1; j < 33; ++j) {
      float Bj = P[(size_t)(j - 1) * NF + k];
      const float* cw = AWZT + j * 32;
      const float* cp = APT + j * 32;
#pragma unroll
      for (int i = 0; i < 32; ++i) {
        accW[i] += cw[i] * Bj;
        accP[i] += cp[i] * Bj;
      }
    }
#pragma unroll
    for (int i = 0; i < 32; ++i) out[OUT_WZ + (size_t)i * NF + k] = accW[i];
#pragma unroll
    for (int i = 0; i < 32; ++i) out[OUT_P + (size_t)i * NF + k] = accP[i];
  } else {
    const int k = (b - 1024) * 256 + tid;
    float yv = y[k], mv = muy[k];
    float mn = (mv * n1 + yv) * inv;
    out[OUT_MU_Y + k] = mn;
    float accC[32];
#pragma unroll
    for (int i = 0; i < 32; ++i) accC[i] = 0.f;
    {
      float B0 = yv - mn;
#pragma unroll
      for (int i = 0; i < 32; ++i) accC[i] += ACZT[i] * B0;
    }
#pragma unroll 4
    for (int j = 1; j < 33; ++j) {
      float Bj = Cz[(size_t)(j - 1) * NT + k];
      const float* cc = ACZT + j * 32;
#pragma unroll
      for (int i = 0; i < 32; ++i) accC[i] += cc[i] * Bj;
    }
#pragma unroll
    for (int i = 0; i < 32; ++i) out[OUT_CZ + (size_t)i * NT + k] = accC[i];
  }
}

extern "C" void kernel_launch(void* const* d_in, const int* in_sizes, int n_in,
                              void* d_out, int out_size, void* d_ws, size_t ws_size,
                              hipStream_t stream) {
  const float* x   = (const float*)d_in[0];
  const float* y   = (const float*)d_in[1];
  const float* mux = (const float*)d_in[2];
  const float* muy = (const float*)d_in[3];
  const float* u   = (const float*)d_in[4];
  const float* Wz  = (const float*)d_in[5];
  const float* Cz  = (const float*)d_in[6];
  const float* tss = (const float*)d_in[7];
  const float* bz  = (const float*)d_in[8];
  const float* P   = (const float*)d_in[9];
  const int*   n   = (const int*)d_in[10];
  float* ws  = (float*)d_ws;
  float* out = (float*)d_out;

  // only GY is atomically accumulated -> zero just that region
  hipMemsetAsync(ws + WS_GY, 0, (size_t)(GYS * GYS) * sizeof(float), stream);
  gram_kernel<<<NBX + NBY, 320, 0, stream>>>(x, y, mux, muy, Wz, Cz, P, n, ws);
  reduce1_kernel<<<NCH * 10, 256, 0, stream>>>(ws);
  reduce2_kernel<<<10, 256, 0, stream>>>(ws);
  solve_kernel<<<1, 64, 0, stream>>>(ws, u, tss, bz, ws + WS_COEF, out);
  out_kernel<<<1024 + 32, 256, 0, stream>>>(x, y, mux, muy, Wz, Cz, P, n, ws + WS_COEF, out);
}

// Round 5
// 266.246 us; speedup vs baseline: 1.5491x; 1.5491x over previous
//
#include <hip/hip_runtime.h>

// IPLS partial_fit (n > BURN_IN). Gram-reformulated:
//   x-side Gram 65x65 of [xc, P_0..31, Wz_0..31], y-side 33x33 of [yc, Cz_0..31]
//   -> 1-wave f64 scalar recurrence solve -> skinny 64x33 output combine.
// R5: gram reverted to R3 config (256-float windows, unroll 4, VGPR 84 -- the
// 128-float/full-unroll variant spilled: VGPR 128 + 480MB scratch traffic).
// Keeps R4's register-preloaded solve and j-outer out_kernel.

#define NF 262144
#define NT 8192
#define NL 32
#define GXS 68
#define GYS 36
#define NBX 512          // x-side gram blocks (each: 2 windows of 256 floats)
#define NBY 32           // y-side gram blocks (1 window of 256)
#define NPAIR 66         // 11 groups of 6 rows -> 66 group-pairs
#define ENT (NPAIR*36)   // 2376 partial entries per block
#define NCH 32           // stage-1 reduce chunks
#define CHSZ (NBX/NCH)   // 16 slices per chunk

#define WS_PART  0
#define WS_PART2 (NBX*ENT)                   // 1216512
#define WS_GY    (WS_PART2 + NCH*ENT)        // 1292544
#define WS_GX    (WS_GY + GYS*GYS)           // 1293840
#define WS_COEF  (WS_GX + GXS*GXS)           // 1298464 (3*33*32 floats, transposed)

#define OUT_MU_X 0
#define OUT_MU_Y 262144
#define OUT_U    270336
#define OUT_WZ   270368
#define OUT_CZ   8658976
#define OUT_TSS  8921120
#define OUT_BZ   8921152
#define OUT_P    8921184

#define LDSW 260   // row stride (floats): 256 + 4 pad

__device__ __forceinline__ float4 ld4(const float* p) { return *(const float4*)p; }

__global__ __launch_bounds__(320) void gram_kernel(
    const float* __restrict__ x, const float* __restrict__ y,
    const float* __restrict__ mux, const float* __restrict__ muy,
    const float* __restrict__ Wz, const float* __restrict__ Cz,
    const float* __restrict__ P, const int* __restrict__ np,
    float* __restrict__ ws)
{
  __shared__ float lds[66 * LDSW];   // 68.6 KB
  const int tid = threadIdx.x;
  const int b = blockIdx.x;
  const float n1 = (float)(np[0] + 1);
  const float cmu = n1 / (n1 + 1.0f);   // xc = cmu*(x - mu_old)

  if (b < NBX) {
    // ---- x-side: 66 rows (xc, P_0..31, Wz_0..31, zero), 6-row groups ----
    const int q = tid & 3;
    const int pidx = tid >> 2;
    int gu = 0, gv = 0; bool active = (tid < 264);
    if (active) {
      int pp = pidx;
      for (int g = 0; g < 11; ++g) {
        int c = 11 - g;
        if (pp < c) { gu = g; gv = g + pp; break; }
        pp -= c;
      }
    }
    float acc[36];
#pragma unroll
    for (int i = 0; i < 36; ++i) acc[i] = 0.f;

    for (int w = 0; w < 2; ++w) {
      const int wb = b * 512 + w * 256;
      for (int it = 0; it < 14; ++it) {
        int idx = tid + it * 320;
        if (idx < 4224) {
          int row = idx >> 6;
          int c4 = idx & 63;
          int k = wb + c4 * 4;
          float4 v;
          if (row == 0) {
            float4 xv = ld4(x + k), mv = ld4(mux + k);
            v.x = cmu * (xv.x - mv.x); v.y = cmu * (xv.y - mv.y);
            v.z = cmu * (xv.z - mv.z); v.w = cmu * (xv.w - mv.w);
          } else if (row < 33) {
            v = ld4(P + (size_t)(row - 1) * NF + k);
          } else if (row < 65) {
            v = ld4(Wz + (size_t)(row - 33) * NF + k);
          } else {
            v = make_float4(0.f, 0.f, 0.f, 0.f);
          }
          *(float4*)&lds[row * LDSW + c4 * 4] = v;
        }
      }
      __syncthreads();
      if (active) {
        const int ub = 6 * gu * LDSW, vb = 6 * gv * LDSW;
#pragma unroll 4
        for (int cc = 0; cc < 16; ++cc) {
          const int co = (q + cc * 4) * 4;
          float4 av[6], bv[6];
#pragma unroll
          for (int r = 0; r < 6; ++r) av[r] = *(const float4*)&lds[ub + r * LDSW + co];
#pragma unroll
          for (int s = 0; s < 6; ++s) bv[s] = *(const float4*)&lds[vb + s * LDSW + co];
#pragma unroll
          for (int r = 0; r < 6; ++r)
#pragma unroll
            for (int s = 0; s < 6; ++s)
              acc[r * 6 + s] += av[r].x * bv[s].x + av[r].y * bv[s].y +
                                av[r].z * bv[s].z + av[r].w * bv[s].w;
        }
      }
      __syncthreads();
    }
    // combine the 4 quarters (adjacent lanes within a wave)
#pragma unroll
    for (int e = 0; e < 36; ++e) {
      acc[e] += __shfl_xor(acc[e], 1, 64);
      acc[e] += __shfl_xor(acc[e], 2, 64);
    }
    if (active && q == 0) {
      float* PB = ws + WS_PART + (size_t)b * ENT + pidx * 36;
#pragma unroll
      for (int e4 = 0; e4 < 9; ++e4)
        *(float4*)&PB[e4 * 4] = make_float4(acc[e4 * 4], acc[e4 * 4 + 1],
                                            acc[e4 * 4 + 2], acc[e4 * 4 + 3]);
    }
  } else {
    // ---- y-side: 36 rows (yc, Cz_0..31, zeros), 4-row groups, 45 pairs ----
    float* GY = ws + WS_GY;
    const int yb = b - NBX;
    int gu = 0, gv = 0; bool active = (tid < 45);
    if (active) {
      int pp = tid;
      for (int g = 0; g < 9; ++g) {
        int c = 9 - g;
        if (pp < c) { gu = g; gv = g + pp; break; }
        pp -= c;
      }
    }
    float acc[16];
#pragma unroll
    for (int i = 0; i < 16; ++i) acc[i] = 0.f;
    const int wb = yb * 256;
    for (int it = 0; it < 8; ++it) {
      int idx = tid + it * 320;
      if (idx < 2304) {
        int row = idx >> 6;
        int c4 = idx & 63;
        int k = wb + c4 * 4;
        float4 v;
        if (row == 0) {
          float4 yv = ld4(y + k), mv = ld4(muy + k);
          v.x = cmu * (yv.x - mv.x); v.y = cmu * (yv.y - mv.y);
          v.z = cmu * (yv.z - mv.z); v.w = cmu * (yv.w - mv.w);
        } else if (row < 33) {
          v = ld4(Cz + (size_t)(row - 1) * NT + k);
        } else {
          v = make_float4(0.f, 0.f, 0.f, 0.f);
        }
        *(float4*)&lds[row * LDSW + c4 * 4] = v;
      }
    }
    __syncthreads();
    if (active) {
      const int ub = 4 * gu * LDSW, vb = 4 * gv * LDSW;
      for (int c = 0; c < 64; ++c) {
        float4 av[4], bv[4];
#pragma unroll
        for (int r = 0; r < 4; ++r) av[r] = *(const float4*)&lds[ub + r * LDSW + c * 4];
#pragma unroll
        for (int s = 0; s < 4; ++s) bv[s] = *(const float4*)&lds[vb + s * LDSW + c * 4];
#pragma unroll
        for (int r = 0; r < 4; ++r)
#pragma unroll
          for (int s = 0; s < 4; ++s)
            acc[r * 4 + s] += av[r].x * bv[s].x + av[r].y * bv[s].y +
                              av[r].z * bv[s].z + av[r].w * bv[s].w;
      }
#pragma unroll
      for (int r = 0; r < 4; ++r)
#pragma unroll
        for (int s = 0; s < 4; ++s) {
          int u = 4 * gu + r, v = 4 * gv + s;
          if (u < 33 && v < 33) {
            float val = acc[r * 4 + s];
            atomicAdd(&GY[u * GYS + v], val);
            if (gu != gv) atomicAdd(&GY[v * GYS + u], val);
          }
        }
    }
  }
}

// stage 1: 512 slices -> 32 chunk partials (coalesced)
__global__ __launch_bounds__(256) void reduce1_kernel(float* __restrict__ ws) {
  const int c = blockIdx.x / 10, eb = blockIdx.x % 10;
  const int e = eb * 256 + threadIdx.x;
  if (e < ENT) {
    const float* PB = ws + WS_PART + (size_t)c * CHSZ * ENT;
    float s = 0.f;
#pragma unroll
    for (int j = 0; j < CHSZ; ++j) s += PB[(size_t)j * ENT + e];
    ws[WS_PART2 + (size_t)c * ENT + e] = s;
  }
}

// stage 2: 32 chunk partials -> GX (scatter to 68x68 mirrored layout)
__global__ __launch_bounds__(256) void reduce2_kernel(float* __restrict__ ws) {
  const int e = blockIdx.x * 256 + threadIdx.x;
  if (e < ENT) {
    float s = 0.f;
#pragma unroll
    for (int c = 0; c < NCH; ++c) s += ws[WS_PART2 + (size_t)c * ENT + e];
    int p = e / 36, rs = e % 36;
    int gu = 0, gv = 0, pp = p;
    for (int g = 0; g < 11; ++g) {
      int cN = 11 - g;
      if (pp < cN) { gu = g; gv = g + pp; break; }
      pp -= cN;
    }
    int u = 6 * gu + rs / 6, v = 6 * gv + rs % 6;
    float* GX = ws + WS_GX;
    GX[u * GXS + v] = s;
    if (gu != gv) GX[v * GXS + u] = s;
  }
}

// One wave: f64 scalar recurrences for all 32 components; Gram rows preloaded
// into registers; i-loop fully unrolled (compile-time __shfl indices).
// Coef matrices stored TRANSPOSED: A*T[j*32 + i], j=0..32 basis, i component.
__global__ void solve_kernel(const float* __restrict__ ws,
                             const float* __restrict__ u_in,
                             const float* __restrict__ tss_in,
                             const float* __restrict__ bz_in,
                             float* __restrict__ coef,
                             float* __restrict__ out)
{
  const int l = threadIdx.x;  // 0..63
  const float* GX = ws + WS_GX;
  const float* GY = ws + WS_GY;
  float* AWZT = coef;               // 33 x 32
  float* APT  = coef + 33 * NL;     // 33 x 32 (+P_i identity folded)
  float* ACZT = coef + 66 * NL;     // 33 x 32 (+Cz_i identity folded)

  float rP[32], rW[32], rC[32];
#pragma unroll
  for (int i = 0; i < 32; ++i) rP[i] = GX[(1 + i) * GXS + 1 + l];
#pragma unroll
  for (int i = 0; i < 32; ++i) rW[i] = GX[(1 + i) * GXS + 33 + l];
#pragma unroll
  for (int i = 0; i < 32; ++i) rC[i] = GY[(1 + i) * GYS + 1 + l];
  float dS  = (l < 32) ? GX[(33 + l) * GXS + 33 + l] : 0.f;  // ||Wz_l||^2
  float u0l = (l < 32) ? u_in[l]   : 0.f;
  float t0l = (l < 32) ? tss_in[l] : 0.f;
  float b0l = (l < 32) ? bz_in[l]  : 0.f;

  double q = (double)GX[0];                       // ||xr||^2
  double r = (double)GY[0];                       // ||yr||^2
  double pj = (l < 32) ? (double)GX[1 + l]  : 0.0;
  double wj = (l < 32) ? (double)GX[33 + l] : 0.0;
  double ej = (l < 32) ? (double)GY[1 + l]  : 0.0;
  double cx = (l == 0) ? 1.0 : 0.0;
  double cy = (l == 0) ? 1.0 : 0.0;

#pragma unroll
  for (int i = 0; i < NL; ++i) {
    double a  = __shfl(wj, i, 64);
    double g  = __shfl(ej, i, 64);
    double pi = __shfl(pj, i, 64);
    double s  = (double)__shfl(dS, i, 64);
    double h  = (double)__shfl(rC[i], i, 64);      // GY diag (1+i,1+i)
    double Pd = (double)__shfl(rP[i], i, 64);      // GX diag (1+i,1+i)
    double u0   = (double)__shfl(u0l, i, 64);
    double tss0 = (double)__shfl(t0l, i, 64);
    double bz0  = (double)__shfl(b0l, i, 64);

    double ui = u0, u1 = 0.0, tz = 0.0, tss_ = 0.0, t = 0.0, ncz = 1.0;
#pragma unroll
    for (int pass = 0; pass < 2; ++pass) {
      double num = a + ui * q;
      double den = sqrt(s + 2.0 * ui * a + ui * ui * q) + 1e-7;
      tz = num / den;
      tss_ = tss0 + tz * tz;
      t = tz / sqrt(tss_);
      double ncz2 = h + 2.0 * t * g + t * t * r;
      ncz = sqrt(ncz2);
      ui = (g + t * r) / ncz;
      if (pass == 0) u1 = ui;
    }
    double u2 = ui;
    double bz_new = bz0 + u2 * tz;
    double bb = bz_new / sqrt(tss_);
    double phi = 1.0 - t * t;            // xr' = phi*xr - t*P_i
    double gam = bb * t / ncz;           // yr' = psi*yr - gam*Cz_i
    double psi = 1.0 - gam * t;

    if (l == 0) {
      out[OUT_U + i]   = (float)u2;
      out[OUT_TSS + i] = (float)tss_;
      out[OUT_BZ + i]  = (float)bz_new;
    }
    if (l < 33) {
      AWZT[l * 32 + i] = (float)(u1 * cx);
      APT [l * 32 + i] = (float)(t  * cx) + ((l == 1 + i) ? 1.0f : 0.0f);
      ACZT[l * 32 + i] = (float)(t  * cy) + ((l == 1 + i) ? 1.0f : 0.0f);
    }
    q = phi * phi * q - 2.0 * phi * t * pi + t * t * Pd;
    r = psi * psi * r - 2.0 * psi * gam * g + gam * gam * h;
    cx *= phi; if (l == 1 + i) cx -= t;
    cy *= psi; if (l == 1 + i) cy -= gam;
    if (l < 32) {
      pj = phi * pj - t * (double)rP[i];
      wj = phi * wj - t * (double)rW[i];
      ej = psi * ej - gam * (double)rC[i];
    }
  }
}

// j-outer, 64 resident f32 accumulators per thread: B_j loaded once, consumed.
__global__ __launch_bounds__(256) void out_kernel(
    const float* __restrict__ x, const float* __restrict__ y,
    const float* __restrict__ mux, const float* __restrict__ muy,
    const float* __restrict__ Wz, const float* __restrict__ Cz,
    const float* __restrict__ P, const int* __restrict__ np,
    const float* __restrict__ coef, float* __restrict__ out)
{
  const int b = blockIdx.x, tid = threadIdx.x;
  const float n1 = (float)(np[0] + 1);
  const float inv = 1.0f / (n1 + 1.0f);
  const float* AWZT = coef;
  const float* APT  = coef + 33 * NL;
  const float* ACZT = coef + 66 * NL;

  if (b < 1024) {
    const int k = b * 256 + tid;
    float xv = x[k], mv = mux[k];
    float mn = (mv * n1 + xv) * inv;
    out[OUT_MU_X + k] = mn;
    float accW[32], accP[32];
#pragma unroll
    for (int i = 0; i < 32; ++i) accW[i] = Wz[(size_t)i * NF + k];
#pragma unroll
    for (int i = 0; i < 32; ++i) accP[i] = 0.f;
    {
      float B0 = xv - mn;
#pragma unroll
      for (int i = 0; i < 32; ++i) {
        accW[i] += AWZT[i] * B0;
        accP[i] += APT[i] * B0;
      }
    }
#pragma unroll 4
    for (int j = 1; j < 33; ++j) {
      float Bj = P[(size_t)(j - 1) * NF + k];
      const float* cw = AWZT + j * 32;
      const float* cp = APT + j * 32;
#pragma unroll
      for (int i = 0; i < 32; ++i) {
        accW[i] += cw[i] * Bj;
        accP[i] += cp[i] * Bj;
      }
    }
#pragma unroll
    for (int i = 0; i < 32; ++i) out[OUT_WZ + (size_t)i * NF + k] = accW[i];
#pragma unroll
    for (int i = 0; i < 32; ++i) out[OUT_P + (size_t)i * NF + k] = accP[i];
  } else {
    const int k = (b - 1024) * 256 + tid;
    float yv = y[k], mv = muy[k];
    float mn = (mv * n1 + yv) * inv;
    out[OUT_MU_Y + k] = mn;
    float accC[32];
#pragma unroll
    for (int i = 0; i < 32; ++i) accC[i] = 0.f;
    {
      float B0 = yv - mn;
#pragma unroll
      for (int i = 0; i < 32; ++i) accC[i] += ACZT[i] * B0;
    }
#pragma unroll 4
    for (int j = 1; j < 33; ++j) {
      float Bj = Cz[(size_t)(j - 1) * NT + k];
      const float* cc = ACZT + j * 32;
#pragma unroll
      for (int i = 0; i < 32; ++i) accC[i] += cc[i] * Bj;
    }
#pragma unroll
    for (int i = 0; i < 32; ++i) out[OUT_CZ + (size_t)i * NT + k] = accC[i];
  }
}

extern "C" void kernel_launch(void* const* d_in, const int* in_sizes, int n_in,
                              void* d_out, int out_size, void* d_ws, size_t ws_size,
                              hipStream_t stream) {
  const float* x   = (const float*)d_in[0];
  const float* y   = (const float*)d_in[1];
  const float* mux = (const float*)d_in[2];
  const float* muy = (const float*)d_in[3];
  const float* u   = (const float*)d_in[4];
  const float* Wz  = (const float*)d_in[5];
  const float* Cz  = (const float*)d_in[6];
  const float* tss = (const float*)d_in[7];
  const float* bz  = (const float*)d_in[8];
  const float* P   = (const float*)d_in[9];
  const int*   n   = (const int*)d_in[10];
  float* ws  = (float*)d_ws;
  float* out = (float*)d_out;

  // only GY is atomically accumulated -> zero just that region
  hipMemsetAsync(ws + WS_GY, 0, (size_t)(GYS * GYS) * sizeof(float), stream);
  gram_kernel<<<NBX + NBY, 320, 0, stream>>>(x, y, mux, muy, Wz, Cz, P, n, ws);
  reduce1_kernel<<<NCH * 10, 256, 0, stream>>>(ws);
  reduce2_kernel<<<10, 256, 0, stream>>>(ws);
  solve_kernel<<<1, 64, 0, stream>>>(ws, u, tss, bz, ws + WS_COEF, out);
  out_kernel<<<1024 + 32, 256, 0, stream>>>(x, y, mux, muy, Wz, Cz, P, n, ws + WS_COEF, out);
}